// Round 3
// baseline (386.090 us; speedup 1.0000x reference)
//
#include <hip/hip_runtime.h>
#include <math.h>

namespace {
constexpr int BB = 32, NPG = 4096, NTOT = BB*NPG, C = 128, FIN = 64, KK = 32, JJ = 40;
constexpr int YROWS = BB*JJ; // 1280
constexpr float EPS = 1e-5f;

// CW (precomputed folded constants) float offsets
constexpr int CW_WU  = 0;      // [64][32] Wu[d][k] = sum_c W[c][d]*U[c][k]
constexpr int CW_WV  = 2048;   // [64][32] Wv[d][k] = sum_c W[c][d]*V[c][k]
constexpr int CW_VU  = 4096;   // [32][32] VU[k'][k] = sum_c V[c][k']*U[c][k]
constexpr int CW_WG  = 5120;   // [64]     sum_c W[c][d]*gw[c]
constexpr int CW_VGX = 5184;   // [32]     sum_c V[c][k]*gw[c]
constexpr int CW_VGH = 5216;   // [32]     sum_c V[c][k]*gw[128+c]
constexpr int CW_CBU = 5248;   // [32]     sum_c b[c]*U[c][k]
constexpr int CW_CSU = 5280;   // [32]     sum_c U[c][k]
constexpr int CW_CBV = 5312;   // [32]     sum_c b[c]*V[c][k]
constexpr int CW_CSV = 5344;   // [32]     sum_c V[c][k]
constexpr int CW_SC  = 5376;   // bG = b.gw[0:128], sG = sum gw[0:128]
constexpr int CW_G   = 5384;   // [64][64] G[d][e] = sum_c W[c][d]*W[c][e]
constexpr int CW_WB  = 9480;   // [64]     wb[d] = sum_c W[c][d]*b[c]
constexpr int CW_SW  = 9544;   // [64]     sw[d] = sum_c W[c][d]
constexpr int CW_SB  = 9608;   // sb = sum b, sb2 = sum b^2
constexpr int CW_SIZE = 9610;

// workspace layout (float offsets), all fp32 except ST (double)
constexpr size_t XU_OFF  = 0;                               // NTOT*32
constexpr size_t GX_OFF  = XU_OFF + (size_t)NTOT*KK;        // NTOT
constexpr size_t YP_OFF  = GX_OFF + (size_t)NTOT;           // 1280*32
constexpr size_t PMA_OFF = YP_OFF + (size_t)YROWS*KK;       // 32*40*64
constexpr size_t PSA_OFF = PMA_OFF + 81920;
constexpr size_t PMB_OFF = PSA_OFF + 81920;
constexpr size_t PSB_OFF = PMB_OFF + 81920;
constexpr size_t CWS_OFF = PSB_OFF + 81920;
constexpr size_t ST_OFF  = CWS_OFF + CW_SIZE;               // 4 doubles (even float offset)
}

#define ACC8(A, wv, u0, u1) do { \
  A[0] += (wv)*(u0).x; A[1] += (wv)*(u0).y; A[2] += (wv)*(u0).z; A[3] += (wv)*(u0).w; \
  A[4] += (wv)*(u1).x; A[5] += (wv)*(u1).y; A[6] += (wv)*(u1).z; A[7] += (wv)*(u1).w; } while(0)

__device__ __forceinline__ float dot4(const float4 a, const float4 b) {
  return a.x*b.x + a.y*b.y + a.z*b.z + a.w*b.w;
}
__device__ __forceinline__ float4 f4fma(const float s, const float4 v, float4 acc) {
  acc.x += s*v.x; acc.y += s*v.y; acc.z += s*v.z; acc.w += s*v.w; return acc;
}
__device__ __forceinline__ float4 relu4(const float4 v) {
  return make_float4(fmaxf(v.x,0.f), fmaxf(v.y,0.f), fmaxf(v.z,0.f), fmaxf(v.w,0.f));
}

// ---------------------------------------------------------------------------
// K0: fold W/U/V/gate into small matrices. Block 0: WU/WV/VU/gate folds.
// Block 1: G = W^T W, wb, sw, sb/sb2.
// ---------------------------------------------------------------------------
__global__ __launch_bounds__(256)
void k_pre(const float* __restrict__ W, const float* __restrict__ b,
           const float* __restrict__ U, const float* __restrict__ V,
           const float* __restrict__ gw, float* __restrict__ CWo) {
  __shared__ float W_l[128*64];
  __shared__ float V_l[128*32];
  const int t = threadIdx.x;
  for (int f = t; f < 2048; f += 256) *(float4*)(W_l + 4*f) = *(const float4*)(W + 4*f);
  if (blockIdx.x == 0)
    for (int f = t; f < 1024; f += 256) *(float4*)(V_l + 4*f) = *(const float4*)(V + 4*f);
  __syncthreads();
  if (blockIdx.x == 1) {
    const int d = t >> 2, e0 = (t & 3) * 16;
    float g[16];
    #pragma unroll
    for (int i = 0; i < 16; ++i) g[i] = 0.f;
    for (int c = 0; c < 128; ++c) {
      const float wv = W_l[c*64 + d];
      #pragma unroll
      for (int u = 0; u < 4; ++u) {
        const float4 we = *(const float4*)(W_l + c*64 + e0 + 4*u);
        g[4*u+0] += wv*we.x; g[4*u+1] += wv*we.y;
        g[4*u+2] += wv*we.z; g[4*u+3] += wv*we.w;
      }
    }
    #pragma unroll
    for (int u = 0; u < 4; ++u)
      *(float4*)(CWo + CW_G + d*64 + e0 + 4*u) = make_float4(g[4*u],g[4*u+1],g[4*u+2],g[4*u+3]);
    if (t < 64) {
      float awb = 0.f, asw = 0.f;
      for (int c = 0; c < 128; ++c) {
        const float wv = W_l[c*64 + t];
        awb += wv * b[c]; asw += wv;
      }
      CWo[CW_WB + t] = awb; CWo[CW_SW + t] = asw;
    }
    if (t == 0) {
      float sb = 0.f, sb2 = 0.f;
      for (int c = 0; c < 128; ++c) { sb += b[c]; sb2 += b[c]*b[c]; }
      CWo[CW_SB+0] = sb; CWo[CW_SB+1] = sb2;
    }
    return;
  }
  {
    const int d = t >> 2, k0 = (t & 3) * 8;
    float au[8] = {0,0,0,0,0,0,0,0};
    float av[8] = {0,0,0,0,0,0,0,0};
    for (int c = 0; c < 128; ++c) {
      const float wv = W_l[c*64 + d];
      const float4 u0 = *(const float4*)(U + c*32 + k0);
      const float4 u1 = *(const float4*)(U + c*32 + k0 + 4);
      ACC8(au, wv, u0, u1);
      const float4 v0 = *(const float4*)(V_l + c*32 + k0);
      const float4 v1 = *(const float4*)(V_l + c*32 + k0 + 4);
      ACC8(av, wv, v0, v1);
    }
    *(float4*)(CWo + CW_WU + d*32 + k0)     = make_float4(au[0],au[1],au[2],au[3]);
    *(float4*)(CWo + CW_WU + d*32 + k0 + 4) = make_float4(au[4],au[5],au[6],au[7]);
    *(float4*)(CWo + CW_WV + d*32 + k0)     = make_float4(av[0],av[1],av[2],av[3]);
    *(float4*)(CWo + CW_WV + d*32 + k0 + 4) = make_float4(av[4],av[5],av[6],av[7]);
  }
  if (t < 128) {
    const int kp = t >> 2, k0 = (t & 3) * 8;
    float a[8] = {0,0,0,0,0,0,0,0};
    for (int c = 0; c < 128; ++c) {
      const float vv = V_l[c*32 + kp];
      const float4 u0 = *(const float4*)(U + c*32 + k0);
      const float4 u1 = *(const float4*)(U + c*32 + k0 + 4);
      ACC8(a, vv, u0, u1);
    }
    *(float4*)(CWo + CW_VU + kp*32 + k0)     = make_float4(a[0],a[1],a[2],a[3]);
    *(float4*)(CWo + CW_VU + kp*32 + k0 + 4) = make_float4(a[4],a[5],a[6],a[7]);
  }
  if (t < 64) {
    float a = 0.f;
    for (int c = 0; c < 128; ++c) a += W_l[c*64 + t] * gw[c];
    CWo[CW_WG + t] = a;
  }
  if (t < 32) {
    float a1=0,a2=0,a3=0,a4=0,a5=0,a6=0;
    for (int c = 0; c < 128; ++c) {
      const float uv = U[c*32 + t], vv = V_l[c*32 + t], bc = b[c];
      a1 += vv*gw[c]; a2 += vv*gw[128+c];
      a3 += bc*uv;    a4 += uv;
      a5 += bc*vv;    a6 += vv;
    }
    CWo[CW_VGX+t]=a1; CWo[CW_VGH+t]=a2; CWo[CW_CBU+t]=a3; CWo[CW_CSU+t]=a4;
    CWo[CW_CBV+t]=a5; CWo[CW_CSV+t]=a6;
  }
  if (t == 0) {
    float bg=0.f, sg=0.f;
    for (int c = 0; c < 128; ++c) { bg += b[c]*gw[c]; sg += gw[c]; }
    CWo[CW_SC+0]=bg; CWo[CW_SC+1]=sg;
  }
}

// ---------------------------------------------------------------------------
// K1: stats via second moments, grid-stride over 64-row tiles; ONE atomic
// pair per block (fix: 4096 same-line atomics serialized ~92us -> 512).
// ---------------------------------------------------------------------------
__global__ __launch_bounds__(256,6)
void k_cov(const float* __restrict__ inp, const float* __restrict__ CW,
           double* __restrict__ stats, const int ntiles) {
  __shared__ float a_l[64*64];
  __shared__ float red[12];
  const int t = threadIdx.x;
  const int dg = t >> 4, eg = t & 15;
  const int d0 = dg*4, e0 = eg*4;
  float av1 = 0.f, av2 = 0.f, avb = 0.f;
  int nt = 0;
  for (int tile = blockIdx.x; tile < ntiles; tile += gridDim.x) {
    __syncthreads();
    const size_t r0 = (size_t)tile * 64;
    #pragma unroll
    for (int s = 0; s < 4; ++s) {
      int f = (t + 256*s) * 4;
      *(float4*)(a_l + f) = *(const float4*)(inp + r0*FIN + f);
    }
    __syncthreads();
    float S[4][4];
    #pragma unroll
    for (int i=0;i<4;i++)
      #pragma unroll
      for (int j=0;j<4;j++) S[i][j] = 0.f;
    float4 cs = make_float4(0.f,0.f,0.f,0.f);
    #pragma unroll 4
    for (int r = 0; r < 64; ++r) {
      const float4 ad = *(const float4*)(a_l + r*64 + d0);
      const float4 ae = *(const float4*)(a_l + r*64 + e0);
      S[0][0]+=ad.x*ae.x; S[0][1]+=ad.x*ae.y; S[0][2]+=ad.x*ae.z; S[0][3]+=ad.x*ae.w;
      S[1][0]+=ad.y*ae.x; S[1][1]+=ad.y*ae.y; S[1][2]+=ad.y*ae.z; S[1][3]+=ad.y*ae.w;
      S[2][0]+=ad.z*ae.x; S[2][1]+=ad.z*ae.y; S[2][2]+=ad.z*ae.z; S[2][3]+=ad.z*ae.w;
      S[3][0]+=ad.w*ae.x; S[3][1]+=ad.w*ae.y; S[3][2]+=ad.w*ae.z; S[3][3]+=ad.w*ae.w;
      cs.x += ad.x; cs.y += ad.y; cs.z += ad.z; cs.w += ad.w;
    }
    #pragma unroll
    for (int i = 0; i < 4; ++i) {
      const float4 g4 = *(const float4*)(CW + CW_G + (d0+i)*64 + e0);
      av2 += S[i][0]*g4.x + S[i][1]*g4.y + S[i][2]*g4.z + S[i][3]*g4.w;
    }
    if (eg == 0) {
      const float4 sw4 = *(const float4*)(CW + CW_SW + d0);
      const float4 wb4 = *(const float4*)(CW + CW_WB + d0);
      av1 += cs.x*sw4.x + cs.y*sw4.y + cs.z*sw4.z + cs.w*sw4.w;
      avb += cs.x*wb4.x + cs.y*wb4.y + cs.z*wb4.z + cs.w*wb4.w;
    }
    ++nt;
  }
  #pragma unroll
  for (int off = 32; off > 0; off >>= 1) {
    av2 += __shfl_xor(av2, off);
    av1 += __shfl_xor(av1, off);
    avb += __shfl_xor(avb, off);
  }
  const int w = t >> 6;
  if ((t & 63) == 0) { red[w*3] = av1; red[w*3+1] = av2; red[w*3+2] = avb; }
  __syncthreads();
  if (t == 0) {
    const float sb = CW[CW_SB], sb2 = CW[CW_SB+1];
    const double rowsB = 64.0 * (double)nt;
    const double s1 = (double)(red[0]+red[3]+red[6]+red[9]);
    const double s2 = (double)(red[1]+red[4]+red[7]+red[10]);
    const double sB = (double)(red[2]+red[5]+red[8]+red[11]);
    atomicAdd(stats+0, s1 + rowsB*(double)sb);
    atomicAdd(stats+1, s2 + 2.0*sB + rowsB*(double)sb2);
  }
}

// ---------------------------------------------------------------------------
// irow2x: per (kq8, rr) thread, compute I j-quad (4m..4m+3) for rows rr and
// rr+32; dot over this lane's 4 k's then 8-lane reduce (xor 1,2,4) -> full.
// ---------------------------------------------------------------------------
__device__ __forceinline__ void irow2x(const float* ypj, const int kq8, const int m,
                                       const float4 xp0, const float4 xp1,
                                       float4& a0, float4& a1) {
  const float4 y0 = *(const float4*)(ypj + (4*m+0)*32 + kq8*4);
  const float4 y1 = *(const float4*)(ypj + (4*m+1)*32 + kq8*4);
  const float4 y2 = *(const float4*)(ypj + (4*m+2)*32 + kq8*4);
  const float4 y3 = *(const float4*)(ypj + (4*m+3)*32 + kq8*4);
  a0.x = dot4(xp0,y0); a0.y = dot4(xp0,y1); a0.z = dot4(xp0,y2); a0.w = dot4(xp0,y3);
  a1.x = dot4(xp1,y0); a1.y = dot4(xp1,y1); a1.z = dot4(xp1,y2); a1.w = dot4(xp1,y3);
  #pragma unroll
  for (int off = 1; off <= 4; off <<= 1) {
    a0.x += __shfl_xor(a0.x, off); a0.y += __shfl_xor(a0.y, off);
    a0.z += __shfl_xor(a0.z, off); a0.w += __shfl_xor(a0.w, off);
    a1.x += __shfl_xor(a1.x, off); a1.y += __shfl_xor(a1.y, off);
    a1.z += __shfl_xor(a1.z, off); a1.w += __shfl_xor(a1.w, off);
  }
}

// ---------------------------------------------------------------------------
// partials_lds: softmax partials (max + sumexp per j) from p staged in LDS
// (stride 44). Old proven reduction pattern; ev loaded from LDS.
// ---------------------------------------------------------------------------
__device__ __forceinline__ void partials_lds(const float* p_l, const int t,
    float* sredm, float* sreds, float* redm,
    float* __restrict__ PmB, float* __restrict__ PsB) {
  const int r2 = t >> 2, kq = t & 3;
  const int w = t >> 6, tl = t & 63;
  float ev[10];
  #pragma unroll
  for (int m = 0; m < 10; ++m) ev[m] = p_l[r2*44 + 4*m + kq];
  float mv[10];
  #pragma unroll
  for (int m = 0; m < 10; ++m) {
    mv[m] = ev[m];
    mv[m] = fmaxf(mv[m], __shfl_xor(mv[m], 4));
    mv[m] = fmaxf(mv[m], __shfl_xor(mv[m], 8));
    mv[m] = fmaxf(mv[m], __shfl_xor(mv[m], 16));
    mv[m] = fmaxf(mv[m], __shfl_xor(mv[m], 32));
  }
  if (tl < 4) {
    #pragma unroll
    for (int m = 0; m < 10; ++m) sredm[w*40 + 4*m + kq] = mv[m];
  }
  __syncthreads();
  if (t < 40)
    redm[t] = fmaxf(fmaxf(sredm[t], sredm[40+t]), fmaxf(sredm[80+t], sredm[120+t]));
  __syncthreads();
  float es[10];
  #pragma unroll
  for (int m = 0; m < 10; ++m) {
    const float M = redm[4*m + kq];
    es[m] = __expf(ev[m]-M);
    es[m] += __shfl_xor(es[m], 4);
    es[m] += __shfl_xor(es[m], 8);
    es[m] += __shfl_xor(es[m], 16);
    es[m] += __shfl_xor(es[m], 32);
  }
  if (tl < 4) {
    #pragma unroll
    for (int m = 0; m < 10; ++m) sreds[w*40 + 4*m + kq] = es[m];
  }
  __syncthreads();
  if (t < 40) {
    PmB[(size_t)t*64] = redm[t];
    PsB[(size_t)t*64] = sreds[t]+sreds[40+t]+sreds[80+t]+sreds[120+t];
  }
}

// ---------------------------------------------------------------------------
// K2: y_p directly from fe: yp = relu(q*relu(ry*(fe@Wv + cbV) - ry*my*csV)).
// ---------------------------------------------------------------------------
__global__ __launch_bounds__(256,4)
void k_yp2(const float* __restrict__ fe, const float* __restrict__ CW,
           const float* __restrict__ q, const double* __restrict__ ST,
           float* __restrict__ yp) {
  __shared__ float in_t[64*64];
  __shared__ float Wl[64*32];
  const int t = threadIdx.x;
  const int r0 = blockIdx.x * 64;
  #pragma unroll
  for (int s = 0; s < 4; ++s) {
    int f = (t + 256*s) * 4;
    int r = f >> 6, d = f & 63;
    float4 v = *(const float4*)(fe + (size_t)r0*FIN + f);
    *(float4*)(in_t + r*64 + (d ^ ((r & 7) * 8))) = v;
  }
  #pragma unroll
  for (int s = 0; s < 2; ++s) {
    int f = (t + 256*s) * 4;
    *(float4*)(Wl + f) = *(const float4*)(CW + CW_WV + f);
  }
  __syncthreads();
  const double cy = (double)YROWS * (double)C;
  const double myd = ST[2]/cy, vy = ST[3]/cy - myd*myd;
  const float ry = (float)(1.0/sqrt(vy + (double)EPS));
  const float mr = (float)myd * ry;
  const int r2 = t >> 2, kq = t & 3;
  const int swz = (r2 & 7) * 8;
  float acc[8] = {0,0,0,0,0,0,0,0};
  #pragma unroll
  for (int dc = 0; dc < 16; ++dc) {
    const int d = dc*4;
    const float4 a = *(const float4*)(in_t + r2*64 + (d ^ swz));
    { const float4 w0 = *(const float4*)(Wl + (d+0)*32 + kq*8);
      const float4 w1 = *(const float4*)(Wl + (d+0)*32 + kq*8 + 4); ACC8(acc, a.x, w0, w1); }
    { const float4 w0 = *(const float4*)(Wl + (d+1)*32 + kq*8);
      const float4 w1 = *(const float4*)(Wl + (d+1)*32 + kq*8 + 4); ACC8(acc, a.y, w0, w1); }
    { const float4 w0 = *(const float4*)(Wl + (d+2)*32 + kq*8);
      const float4 w1 = *(const float4*)(Wl + (d+2)*32 + kq*8 + 4); ACC8(acc, a.z, w0, w1); }
    { const float4 w0 = *(const float4*)(Wl + (d+3)*32 + kq*8);
      const float4 w1 = *(const float4*)(Wl + (d+3)*32 + kq*8 + 4); ACC8(acc, a.w, w0, w1); }
  }
  #pragma unroll
  for (int i = 0; i < 8; ++i) {
    const int k = kq*8 + i;
    const float typ = ry*(acc[i] + CW[CW_CBV+k]) - mr*CW[CW_CSV+k];
    float v = fmaxf(typ, 0.f);
    acc[i] = fmaxf(q[k]*v, 0.f);
  }
  *(float4*)(yp + (size_t)(r0+r2)*KK + kq*8)     = make_float4(acc[0],acc[1],acc[2],acc[3]);
  *(float4*)(yp + (size_t)(r0+r2)*KK + kq*8 + 4) = make_float4(acc[4],acc[5],acc[6],acc[7]);
}

// ---------------------------------------------------------------------------
// K3: layer-0 with (kq8, rr) 2-row mapping: xu quads (no cross-lane reduce in
// GEMM), gx, I via irow2x streamed to LDS (overlay in_t), partials.
// ---------------------------------------------------------------------------
__global__ __launch_bounds__(256,4)
void k_I0(const float* __restrict__ nf, const float* __restrict__ CW,
          const double* __restrict__ ST, const float* __restrict__ yp,
          float* __restrict__ XU, float* __restrict__ GX,
          float* __restrict__ Pm, float* __restrict__ Ps) {
  __shared__ float in_t[64*64];          // later overlaid as p_l (stride 44)
  __shared__ float Wl[64*32];
  __shared__ float ypj[40*32];
  __shared__ float wgl[64];
  __shared__ float sredm[160], sreds[160], redm[40];
  const int t = threadIdx.x;
  const int bid = blockIdx.x;
  const int b = bid >> 6, blk = bid & 63;
  const size_t rowbase = (size_t)b*NPG + (size_t)blk*64;
  #pragma unroll
  for (int s = 0; s < 4; ++s) {
    int f = (t + 256*s) * 4;
    int r = f >> 6, d = f & 63;
    float4 v = *(const float4*)(nf + rowbase*FIN + f);
    *(float4*)(in_t + r*64 + (d ^ ((r & 7) * 8))) = v;
  }
  #pragma unroll
  for (int s = 0; s < 2; ++s) {
    int f = (t + 256*s) * 4;
    *(float4*)(Wl + f) = *(const float4*)(CW + CW_WU + f);
  }
  for (int f4v = t; f4v < 320; f4v += 256)
    *(float4*)(ypj + f4v*4) = *(const float4*)(yp + (size_t)b*(JJ*KK) + f4v*4);
  if (t < 64) wgl[t] = CW[CW_WG + t];
  __syncthreads();
  const double cx = (double)NTOT * (double)C;
  const double mx = ST[0]/cx, vx = ST[1]/cx - mx*mx;
  const float rx = (float)(1.0/sqrt(vx + (double)EPS));
  const float mr = (float)mx * rx;
  const int kq8 = t & 7, rr = t >> 3;
  const size_t row0 = rowbase + rr, row1 = rowbase + rr + 32;
  const int swz = (rr & 7) * 8;          // same for rr+32
  float4 xu0 = make_float4(0.f,0.f,0.f,0.f), xu1 = make_float4(0.f,0.f,0.f,0.f);
  #pragma unroll
  for (int dc = 0; dc < 16; ++dc) {
    const int d = dc*4;
    const float4 a0 = *(const float4*)(in_t + rr*64 + (d ^ swz));
    const float4 a1 = *(const float4*)(in_t + (rr+32)*64 + (d ^ swz));
    const float4 w0 = *(const float4*)(Wl + (d+0)*32 + kq8*4);
    const float4 w1 = *(const float4*)(Wl + (d+1)*32 + kq8*4);
    const float4 w2 = *(const float4*)(Wl + (d+2)*32 + kq8*4);
    const float4 w3 = *(const float4*)(Wl + (d+3)*32 + kq8*4);
    xu0 = f4fma(a0.x, w0, xu0); xu0 = f4fma(a0.y, w1, xu0);
    xu0 = f4fma(a0.z, w2, xu0); xu0 = f4fma(a0.w, w3, xu0);
    xu1 = f4fma(a1.x, w0, xu1); xu1 = f4fma(a1.y, w1, xu1);
    xu1 = f4fma(a1.z, w2, xu1); xu1 = f4fma(a1.w, w3, xu1);
  }
  // gx: this lane sums d in kq8*8..+8, 8-lane reduce
  float gp0 = 0.f, gp1 = 0.f;
  #pragma unroll
  for (int u = 0; u < 2; ++u) {
    const int d = kq8*8 + 4*u;
    const float4 a0 = *(const float4*)(in_t + rr*64 + (d ^ swz));
    const float4 a1 = *(const float4*)(in_t + (rr+32)*64 + (d ^ swz));
    const float4 wv = *(const float4*)(wgl + d);
    gp0 += dot4(a0, wv); gp1 += dot4(a1, wv);
  }
  gp0 += __shfl_xor(gp0,1); gp0 += __shfl_xor(gp0,2); gp0 += __shfl_xor(gp0,4);
  gp1 += __shfl_xor(gp1,1); gp1 += __shfl_xor(gp1,2); gp1 += __shfl_xor(gp1,4);
  {
    const float4 cb = *(const float4*)(CW + CW_CBU + kq8*4);
    const float4 cu = *(const float4*)(CW + CW_CSU + kq8*4);
    xu0.x = rx*(xu0.x + cb.x) - mr*cu.x; xu0.y = rx*(xu0.y + cb.y) - mr*cu.y;
    xu0.z = rx*(xu0.z + cb.z) - mr*cu.z; xu0.w = rx*(xu0.w + cb.w) - mr*cu.w;
    xu1.x = rx*(xu1.x + cb.x) - mr*cu.x; xu1.y = rx*(xu1.y + cb.y) - mr*cu.y;
    xu1.z = rx*(xu1.z + cb.z) - mr*cu.z; xu1.w = rx*(xu1.w + cb.w) - mr*cu.w;
  }
  *(float4*)(XU + row0*KK + kq8*4) = xu0;
  *(float4*)(XU + row1*KK + kq8*4) = xu1;
  if (kq8 == 0) {
    GX[row0] = rx*(gp0 + CW[CW_SC+0]) - mr*CW[CW_SC+1];
    GX[row1] = rx*(gp1 + CW[CW_SC+0]) - mr*CW[CW_SC+1];
  }
  const float4 xp0 = relu4(xu0), xp1 = relu4(xu1);
  __syncthreads();                       // all in_t reads done; overlay next
  float* p_l = in_t;
  #pragma unroll
  for (int m = 0; m < 10; ++m) {
    float4 a0, a1;
    irow2x(ypj, kq8, m, xp0, xp1, a0, a1);
    if (kq8 == (m & 7)) {
      *(float4*)(p_l + rr*44 + 4*m) = a0;
      *(float4*)(p_l + (rr+32)*44 + 4*m) = a1;
    }
  }
  __syncthreads();
  partials_lds(p_l, t, sredm, sreds, redm,
               Pm + (size_t)b*2560 + blk, Ps + (size_t)b*2560 + blk);
}

// ---------------------------------------------------------------------------
// K4: fused layer update, (kq8, rr) 2-row mapping throughout:
// I (irow2x) -> e -> h = e@yp -> hu = h@VU + gate -> blend -> new I ->
// partials (or FINAL: out = sigmoid(sum_j I^2)).
// ---------------------------------------------------------------------------
template<int FINAL>
__global__ __launch_bounds__(256,4)
void k_fused2(float* __restrict__ XU, float* __restrict__ GX,
              const float* __restrict__ yp, const float* __restrict__ CW,
              const float* __restrict__ gb,
              const float* __restrict__ PmIn, const float* __restrict__ PsIn,
              float* __restrict__ PmOut, float* __restrict__ PsOut,
              float* __restrict__ outp) {
  __shared__ float ypj[40*32];
  __shared__ float e_l[64*44];           // A-tile; reused as p-stage for partials
  __shared__ float h_l[64*40];
  __shared__ float VUl[32*32];
  __shared__ float M_l[40], Si_l[40];
  __shared__ float vgxl[32], vghl[32];
  __shared__ float sredm[160], sreds[160], redm[40];
  const int t = threadIdx.x;
  const int bid = blockIdx.x;
  const int b = bid >> 6, blk = bid & 63;
  const size_t rowbase = (size_t)b*NPG + (size_t)blk*64;
  if (t < 40) {
    const float* pm = PmIn + ((size_t)b*40 + t)*64;
    const float* ps = PsIn + ((size_t)b*40 + t)*64;
    float M = 0.f;
    for (int k2 = 0; k2 < 64; ++k2) M = fmaxf(M, pm[k2]);
    float S = 0.f;
    for (int k2 = 0; k2 < 64; ++k2) S += ps[k2]*__expf(pm[k2]-M);
    M_l[t] = M; Si_l[t] = 1.f/S;
  }
  for (int f4v = t; f4v < 320; f4v += 256)
    *(float4*)(ypj + f4v*4) = *(const float4*)(yp + (size_t)b*(JJ*KK) + f4v*4);
  *(float4*)(VUl + 4*t) = *(const float4*)(CW + CW_VU + 4*t);
  if (t < 32) { vgxl[t] = CW[CW_VGX+t]; vghl[t] = CW[CW_VGH+t]; }
  __syncthreads();
  const int kq8 = t & 7, rr = t >> 3;
  const size_t row0 = rowbase + rr, row1 = rowbase + rr + 32;
  float4 xu0 = *(const float4*)(XU + row0*KK + kq8*4);
  float4 xu1 = *(const float4*)(XU + row1*KK + kq8*4);
  float4 xp0 = relu4(xu0), xp1 = relu4(xu1);
  // irow1 -> e_l (A tile)
  #pragma unroll
  for (int m = 0; m < 10; ++m) {
    float4 a0, a1;
    irow2x(ypj, kq8, m, xp0, xp1, a0, a1);
    if (kq8 == (m & 7)) {
      float4 e0, e1;
      e0.x = __expf(a0.x - M_l[4*m+0]) * Si_l[4*m+0];
      e0.y = __expf(a0.y - M_l[4*m+1]) * Si_l[4*m+1];
      e0.z = __expf(a0.z - M_l[4*m+2]) * Si_l[4*m+2];
      e0.w = __expf(a0.w - M_l[4*m+3]) * Si_l[4*m+3];
      e1.x = __expf(a1.x - M_l[4*m+0]) * Si_l[4*m+0];
      e1.y = __expf(a1.y - M_l[4*m+1]) * Si_l[4*m+1];
      e1.z = __expf(a1.z - M_l[4*m+2]) * Si_l[4*m+2];
      e1.w = __expf(a1.w - M_l[4*m+3]) * Si_l[4*m+3];
      *(float4*)(e_l + rr*44 + 4*m) = e0;
      *(float4*)(e_l + (rr+32)*44 + 4*m) = e1;
    }
  }
  __syncthreads();
  // phase B: h[n][k-quad] = relu(sum_j e[n][j]*yp[j][k])
  {
    float4 h0 = make_float4(0.f,0.f,0.f,0.f), h1 = make_float4(0.f,0.f,0.f,0.f);
    #pragma unroll
    for (int jc = 0; jc < 10; ++jc) {
      const float4 e40 = *(const float4*)(e_l + rr*44 + 4*jc);
      const float4 e41 = *(const float4*)(e_l + (rr+32)*44 + 4*jc);
      const float4 y0 = *(const float4*)(ypj + (4*jc+0)*32 + kq8*4);
      const float4 y1 = *(const float4*)(ypj + (4*jc+1)*32 + kq8*4);
      const float4 y2 = *(const float4*)(ypj + (4*jc+2)*32 + kq8*4);
      const float4 y3 = *(const float4*)(ypj + (4*jc+3)*32 + kq8*4);
      h0 = f4fma(e40.x, y0, h0); h0 = f4fma(e40.y, y1, h0);
      h0 = f4fma(e40.z, y2, h0); h0 = f4fma(e40.w, y3, h0);
      h1 = f4fma(e41.x, y0, h1); h1 = f4fma(e41.y, y1, h1);
      h1 = f4fma(e41.z, y2, h1); h1 = f4fma(e41.w, y3, h1);
    }
    h0 = relu4(h0); h1 = relu4(h1);
    *(float4*)(h_l + rr*40 + kq8*4) = h0;
    *(float4*)(h_l + (rr+32)*40 + kq8*4) = h1;
  }
  __syncthreads();
  // phase C: hu = h@VU (k-quad out), gate scalars over full kp, blend
  {
    float4 hu0 = make_float4(0.f,0.f,0.f,0.f), hu1 = make_float4(0.f,0.f,0.f,0.f);
    float gh20 = 0.f, gh21 = 0.f, ghx0 = 0.f, ghx1 = 0.f;
    #pragma unroll
    for (int kc = 0; kc < 8; ++kc) {
      const float4 h40 = *(const float4*)(h_l + rr*40 + 4*kc);
      const float4 h41 = *(const float4*)(h_l + (rr+32)*40 + 4*kc);
      const float4 vg = *(const float4*)(vghl + 4*kc);
      const float4 vx = *(const float4*)(vgxl + 4*kc);
      gh20 += dot4(h40, vg); gh21 += dot4(h41, vg);
      ghx0 += dot4(h40, vx); ghx1 += dot4(h41, vx);
      {
        const float4 vu = *(const float4*)(VUl + (4*kc+0)*32 + kq8*4);
        hu0 = f4fma(h40.x, vu, hu0); hu1 = f4fma(h41.x, vu, hu1);
      }
      {
        const float4 vu = *(const float4*)(VUl + (4*kc+1)*32 + kq8*4);
        hu0 = f4fma(h40.y, vu, hu0); hu1 = f4fma(h41.y, vu, hu1);
      }
      {
        const float4 vu = *(const float4*)(VUl + (4*kc+2)*32 + kq8*4);
        hu0 = f4fma(h40.z, vu, hu0); hu1 = f4fma(h41.z, vu, hu1);
      }
      {
        const float4 vu = *(const float4*)(VUl + (4*kc+3)*32 + kq8*4);
        hu0 = f4fma(h40.w, vu, hu0); hu1 = f4fma(h41.w, vu, hu1);
      }
    }
    const float gx0 = GX[row0], gx1 = GX[row1];
    const float gbv = gb[0];
    const float z0 = 1.f/(1.f + __expf(-(gx0 + gh20 + gbv)));
    const float z1 = 1.f/(1.f + __expf(-(gx1 + gh21 + gbv)));
    xu0.x = (1.f-z0)*xu0.x + z0*hu0.x; xu0.y = (1.f-z0)*xu0.y + z0*hu0.y;
    xu0.z = (1.f-z0)*xu0.z + z0*hu0.z; xu0.w = (1.f-z0)*xu0.w + z0*hu0.w;
    xu1.x = (1.f-z1)*xu1.x + z1*hu1.x; xu1.y = (1.f-z1)*xu1.y + z1*hu1.y;
    xu1.z = (1.f-z1)*xu1.z + z1*hu1.z; xu1.w = (1.f-z1)*xu1.w + z1*hu1.w;
    if (!FINAL) {
      *(float4*)(XU + row0*KK + kq8*4) = xu0;
      *(float4*)(XU + row1*KK + kq8*4) = xu1;
      if (kq8 == 0) {
        GX[row0] = (1.f-z0)*gx0 + z0*ghx0;
        GX[row1] = (1.f-z1)*gx1 + z1*ghx1;
      }
    }
    xp0 = relu4(xu0); xp1 = relu4(xu1);
  }
  // irow2: next-layer I
  if (FINAL) {
    float s0 = 0.f, s1 = 0.f;
    #pragma unroll
    for (int m = 0; m < 10; ++m) {
      float4 a0, a1;
      irow2x(ypj, kq8, m, xp0, xp1, a0, a1);
      s0 += dot4(a0, a0); s1 += dot4(a1, a1);
    }
    if (kq8 == 0) {
      outp[row0] = 1.f/(1.f + __expf(-s0));
      outp[row1] = 1.f/(1.f + __expf(-s1));
    }
    return;
  }
  #pragma unroll
  for (int m = 0; m < 10; ++m) {
    float4 a0, a1;
    irow2x(ypj, kq8, m, xp0, xp1, a0, a1);
    if (kq8 == (m & 7)) {                // e_l reads finished before B->C sync
      *(float4*)(e_l + rr*44 + 4*m) = a0;
      *(float4*)(e_l + (rr+32)*44 + 4*m) = a1;
    }
  }
  __syncthreads();
  partials_lds(e_l, t, sredm, sreds, redm,
               PmOut + (size_t)b*2560 + blk, PsOut + (size_t)b*2560 + blk);
}

extern "C" void kernel_launch(void* const* d_in, const int* in_sizes, int n_in,
                              void* d_out, int out_size, void* d_ws, size_t ws_size,
                              hipStream_t stream) {
  const float* nf  = (const float*)d_in[0];
  const float* fe  = (const float*)d_in[1];
  const float* W   = (const float*)d_in[2];
  const float* bin = (const float*)d_in[3];
  const float* U   = (const float*)d_in[4];
  const float* V   = (const float*)d_in[5];
  const float* q   = (const float*)d_in[6];
  const float* gw  = (const float*)d_in[7];
  const float* gb  = (const float*)d_in[8];
  float* out = (float*)d_out;
  float* wf  = (float*)d_ws;

  float* XU  = wf + XU_OFF;
  float* GX  = wf + GX_OFF;
  float* YP  = wf + YP_OFF;
  float* PMa = wf + PMA_OFF;
  float* PSa = wf + PSA_OFF;
  float* PMb = wf + PMB_OFF;
  float* PSb = wf + PSB_OFF;
  float* CWp = wf + CWS_OFF;
  double* ST = (double*)(wf + ST_OFF);

  hipMemsetAsync(ST, 0, 4*sizeof(double), stream);
  k_pre<<<2, 256, 0, stream>>>(W, bin, U, V, gw, CWp);
  k_cov<<<256, 256, 0, stream>>>(nf, CWp, ST, NTOT/64);
  k_cov<<<20, 256, 0, stream>>>(fe, CWp, ST+2, YROWS/64);
  k_yp2<<<YROWS/64, 256, 0, stream>>>(fe, CWp, q, ST, YP);
  k_I0<<<NTOT/64, 256, 0, stream>>>(nf, CWp, ST, YP, XU, GX, PMa, PSa);
  k_fused2<0><<<NTOT/64, 256, 0, stream>>>(XU, GX, YP, CWp, gb, PMa, PSa, PMb, PSb, nullptr);
  k_fused2<1><<<NTOT/64, 256, 0, stream>>>(XU, GX, YP, CWp, gb, PMb, PSb, nullptr, nullptr, out);
}

// Round 4
// 290.359 us; speedup vs baseline: 1.3297x; 1.3297x over previous
//
#include <hip/hip_runtime.h>
#include <math.h>

namespace {
constexpr int BB = 32, NPG = 4096, NTOT = BB*NPG, C = 128, FIN = 64, KK = 32, JJ = 40;
constexpr int YROWS = BB*JJ; // 1280
constexpr float EPS = 1e-5f;

// CW (precomputed folded constants) float offsets
constexpr int CW_WU  = 0;      // [64][32] Wu[d][k] = sum_c W[c][d]*U[c][k]
constexpr int CW_WV  = 2048;   // [64][32] Wv[d][k] = sum_c W[c][d]*V[c][k]
constexpr int CW_VU  = 4096;   // [32][32] VU[k'][k] = sum_c V[c][k']*U[c][k]
constexpr int CW_WG  = 5120;   // [64]     sum_c W[c][d]*gw[c]
constexpr int CW_VGX = 5184;   // [32]     sum_c V[c][k]*gw[c]
constexpr int CW_VGH = 5216;   // [32]     sum_c V[c][k]*gw[128+c]
constexpr int CW_CBU = 5248;   // [32]     sum_c b[c]*U[c][k]
constexpr int CW_CSU = 5280;   // [32]     sum_c U[c][k]
constexpr int CW_CBV = 5312;   // [32]     sum_c b[c]*V[c][k]
constexpr int CW_CSV = 5344;   // [32]     sum_c V[c][k]
constexpr int CW_SC  = 5376;   // bG = b.gw[0:128], sG = sum gw[0:128]
constexpr int CW_G   = 5384;   // [64][64] G[d][e] = sum_c W[c][d]*W[c][e]
constexpr int CW_WB  = 9480;   // [64]     wb[d] = sum_c W[c][d]*b[c]
constexpr int CW_SW  = 9544;   // [64]     sw[d] = sum_c W[c][d]
constexpr int CW_SB  = 9608;   // sb = sum b, sb2 = sum b^2
constexpr int CW_SIZE = 9610;

// workspace layout (float offsets), all fp32 except ST/PB (double)
constexpr size_t XU_OFF  = 0;                               // NTOT*32
constexpr size_t GX_OFF  = XU_OFF + (size_t)NTOT*KK;        // NTOT
constexpr size_t YP_OFF  = GX_OFF + (size_t)NTOT;           // 1280*32
constexpr size_t PMA_OFF = YP_OFF + (size_t)YROWS*KK;       // 32*40*64
constexpr size_t PSA_OFF = PMA_OFF + 81920;
constexpr size_t PMB_OFF = PSA_OFF + 81920;
constexpr size_t PSB_OFF = PMB_OFF + 81920;
constexpr size_t CWS_OFF = PSB_OFF + 81920;
constexpr size_t PBN_OFF = CWS_OFF + 9612;                  // 512 double-pairs (nf)
constexpr size_t PBF_OFF = PBN_OFF + 2048;                  // 20 double-pairs (fe)
constexpr size_t ST_OFF  = PBF_OFF + 80;                    // 4 doubles
}

#define ACC8(A, wv, u0, u1) do { \
  A[0] += (wv)*(u0).x; A[1] += (wv)*(u0).y; A[2] += (wv)*(u0).z; A[3] += (wv)*(u0).w; \
  A[4] += (wv)*(u1).x; A[5] += (wv)*(u1).y; A[6] += (wv)*(u1).z; A[7] += (wv)*(u1).w; } while(0)

// ---------------------------------------------------------------------------
// K0: fold W/U/V/gate into small matrices. Block 0: WU/WV/VU/gate folds.
// Block 1: G = W^T W, wb, sw, sb/sb2.
// ---------------------------------------------------------------------------
__global__ __launch_bounds__(256)
void k_pre(const float* __restrict__ W, const float* __restrict__ b,
           const float* __restrict__ U, const float* __restrict__ V,
           const float* __restrict__ gw, float* __restrict__ CWo) {
  __shared__ float W_l[128*64];
  __shared__ float V_l[128*32];
  const int t = threadIdx.x;
  for (int f = t; f < 2048; f += 256) *(float4*)(W_l + 4*f) = *(const float4*)(W + 4*f);
  if (blockIdx.x == 0)
    for (int f = t; f < 1024; f += 256) *(float4*)(V_l + 4*f) = *(const float4*)(V + 4*f);
  __syncthreads();
  if (blockIdx.x == 1) {
    const int d = t >> 2, e0 = (t & 3) * 16;
    float g[16];
    #pragma unroll
    for (int i = 0; i < 16; ++i) g[i] = 0.f;
    for (int c = 0; c < 128; ++c) {
      const float wv = W_l[c*64 + d];
      #pragma unroll
      for (int u = 0; u < 4; ++u) {
        const float4 we = *(const float4*)(W_l + c*64 + e0 + 4*u);
        g[4*u+0] += wv*we.x; g[4*u+1] += wv*we.y;
        g[4*u+2] += wv*we.z; g[4*u+3] += wv*we.w;
      }
    }
    #pragma unroll
    for (int u = 0; u < 4; ++u)
      *(float4*)(CWo + CW_G + d*64 + e0 + 4*u) = make_float4(g[4*u],g[4*u+1],g[4*u+2],g[4*u+3]);
    if (t < 64) {
      float awb = 0.f, asw = 0.f;
      for (int c = 0; c < 128; ++c) {
        const float wv = W_l[c*64 + t];
        awb += wv * b[c]; asw += wv;
      }
      CWo[CW_WB + t] = awb; CWo[CW_SW + t] = asw;
    }
    if (t == 0) {
      float sb = 0.f, sb2 = 0.f;
      for (int c = 0; c < 128; ++c) { sb += b[c]; sb2 += b[c]*b[c]; }
      CWo[CW_SB+0] = sb; CWo[CW_SB+1] = sb2;
    }
    return;
  }
  {
    const int d = t >> 2, k0 = (t & 3) * 8;
    float au[8] = {0,0,0,0,0,0,0,0};
    float av[8] = {0,0,0,0,0,0,0,0};
    for (int c = 0; c < 128; ++c) {
      const float wv = W_l[c*64 + d];
      const float4 u0 = *(const float4*)(U + c*32 + k0);
      const float4 u1 = *(const float4*)(U + c*32 + k0 + 4);
      ACC8(au, wv, u0, u1);
      const float4 v0 = *(const float4*)(V_l + c*32 + k0);
      const float4 v1 = *(const float4*)(V_l + c*32 + k0 + 4);
      ACC8(av, wv, v0, v1);
    }
    *(float4*)(CWo + CW_WU + d*32 + k0)     = make_float4(au[0],au[1],au[2],au[3]);
    *(float4*)(CWo + CW_WU + d*32 + k0 + 4) = make_float4(au[4],au[5],au[6],au[7]);
    *(float4*)(CWo + CW_WV + d*32 + k0)     = make_float4(av[0],av[1],av[2],av[3]);
    *(float4*)(CWo + CW_WV + d*32 + k0 + 4) = make_float4(av[4],av[5],av[6],av[7]);
  }
  if (t < 128) {
    const int kp = t >> 2, k0 = (t & 3) * 8;
    float a[8] = {0,0,0,0,0,0,0,0};
    for (int c = 0; c < 128; ++c) {
      const float vv = V_l[c*32 + kp];
      const float4 u0 = *(const float4*)(U + c*32 + k0);
      const float4 u1 = *(const float4*)(U + c*32 + k0 + 4);
      ACC8(a, vv, u0, u1);
    }
    *(float4*)(CWo + CW_VU + kp*32 + k0)     = make_float4(a[0],a[1],a[2],a[3]);
    *(float4*)(CWo + CW_VU + kp*32 + k0 + 4) = make_float4(a[4],a[5],a[6],a[7]);
  }
  if (t < 64) {
    float a = 0.f;
    for (int c = 0; c < 128; ++c) a += W_l[c*64 + t] * gw[c];
    CWo[CW_WG + t] = a;
  }
  if (t < 32) {
    float a1=0,a2=0,a3=0,a4=0,a5=0,a6=0;
    for (int c = 0; c < 128; ++c) {
      const float uv = U[c*32 + t], vv = V_l[c*32 + t], bc = b[c];
      a1 += vv*gw[c]; a2 += vv*gw[128+c];
      a3 += bc*uv;    a4 += uv;
      a5 += bc*vv;    a6 += vv;
    }
    CWo[CW_VGX+t]=a1; CWo[CW_VGH+t]=a2; CWo[CW_CBU+t]=a3; CWo[CW_CSU+t]=a4;
    CWo[CW_CBV+t]=a5; CWo[CW_CSV+t]=a6;
  }
  if (t == 0) {
    float bg=0.f, sg=0.f;
    for (int c = 0; c < 128; ++c) { bg += b[c]*gw[c]; sg += gw[c]; }
    CWo[CW_SC+0]=bg; CWo[CW_SC+1]=sg;
  }
}

// ---------------------------------------------------------------------------
// K1: stats via second moments, grid-stride; per-block double-pair to PB
// (NO atomics: round-2 showed same-line f64 atomics serialize ~22ns each).
// ---------------------------------------------------------------------------
__global__ __launch_bounds__(256,6)
void k_cov(const float* __restrict__ inp, const float* __restrict__ CW,
           double* __restrict__ PB, const int ntiles) {
  __shared__ float a_l[64*64];
  __shared__ float red[12];
  const int t = threadIdx.x;
  const int dg = t >> 4, eg = t & 15;
  const int d0 = dg*4, e0 = eg*4;
  float av1 = 0.f, av2 = 0.f, avb = 0.f;
  int nt = 0;
  for (int tile = blockIdx.x; tile < ntiles; tile += gridDim.x) {
    __syncthreads();
    const size_t r0 = (size_t)tile * 64;
    #pragma unroll
    for (int s = 0; s < 4; ++s) {
      int f = (t + 256*s) * 4;
      *(float4*)(a_l + f) = *(const float4*)(inp + r0*FIN + f);
    }
    __syncthreads();
    float S[4][4];
    #pragma unroll
    for (int i=0;i<4;i++)
      #pragma unroll
      for (int j=0;j<4;j++) S[i][j] = 0.f;
    float4 cs = make_float4(0.f,0.f,0.f,0.f);
    #pragma unroll 4
    for (int r = 0; r < 64; ++r) {
      const float4 ad = *(const float4*)(a_l + r*64 + d0);
      const float4 ae = *(const float4*)(a_l + r*64 + e0);
      S[0][0]+=ad.x*ae.x; S[0][1]+=ad.x*ae.y; S[0][2]+=ad.x*ae.z; S[0][3]+=ad.x*ae.w;
      S[1][0]+=ad.y*ae.x; S[1][1]+=ad.y*ae.y; S[1][2]+=ad.y*ae.z; S[1][3]+=ad.y*ae.w;
      S[2][0]+=ad.z*ae.x; S[2][1]+=ad.z*ae.y; S[2][2]+=ad.z*ae.z; S[2][3]+=ad.z*ae.w;
      S[3][0]+=ad.w*ae.x; S[3][1]+=ad.w*ae.y; S[3][2]+=ad.w*ae.z; S[3][3]+=ad.w*ae.w;
      cs.x += ad.x; cs.y += ad.y; cs.z += ad.z; cs.w += ad.w;
    }
    #pragma unroll
    for (int i = 0; i < 4; ++i) {
      const float4 g4 = *(const float4*)(CW + CW_G + (d0+i)*64 + e0);
      av2 += S[i][0]*g4.x + S[i][1]*g4.y + S[i][2]*g4.z + S[i][3]*g4.w;
    }
    if (eg == 0) {
      const float4 sw4 = *(const float4*)(CW + CW_SW + d0);
      const float4 wb4 = *(const float4*)(CW + CW_WB + d0);
      av1 += cs.x*sw4.x + cs.y*sw4.y + cs.z*sw4.z + cs.w*sw4.w;
      avb += cs.x*wb4.x + cs.y*wb4.y + cs.z*wb4.z + cs.w*wb4.w;
    }
    ++nt;
  }
  #pragma unroll
  for (int off = 32; off > 0; off >>= 1) {
    av2 += __shfl_xor(av2, off);
    av1 += __shfl_xor(av1, off);
    avb += __shfl_xor(avb, off);
  }
  const int w = t >> 6;
  if ((t & 63) == 0) { red[w*3] = av1; red[w*3+1] = av2; red[w*3+2] = avb; }
  __syncthreads();
  if (t == 0) {
    const float sb = CW[CW_SB], sb2 = CW[CW_SB+1];
    const double rowsB = 64.0 * (double)nt;
    const double s1 = (double)(red[0]+red[3]+red[6]+red[9]);
    const double s2 = (double)(red[1]+red[4]+red[7]+red[10]);
    const double sB = (double)(red[2]+red[5]+red[8]+red[11]);
    PB[(size_t)blockIdx.x*2 + 0] = s1 + rowsB*(double)sb;
    PB[(size_t)blockIdx.x*2 + 1] = s2 + 2.0*sB + rowsB*(double)sb2;
  }
}

// ---------------------------------------------------------------------------
// K1b: combine per-block double-pairs into ST[0..3]. One block, 256 threads.
// ---------------------------------------------------------------------------
__global__ __launch_bounds__(256)
void k_comb(const double* __restrict__ PBn, const double* __restrict__ PBf,
            double* __restrict__ ST) {
  __shared__ double red[8];
  const int t = threadIdx.x;
  double a = PBn[2*t] + PBn[2*(t+256)];
  double b = PBn[2*t+1] + PBn[2*(t+256)+1];
  #pragma unroll
  for (int off = 32; off > 0; off >>= 1) {
    a += __shfl_down(a, off);
    b += __shfl_down(b, off);
  }
  if ((t & 63) == 0) { red[(t>>6)*2] = a; red[(t>>6)*2+1] = b; }
  __syncthreads();
  if (t == 0) {
    ST[0] = red[0]+red[2]+red[4]+red[6];
    ST[1] = red[1]+red[3]+red[5]+red[7];
  }
  if (t < 64) {
    double c = (t < 20) ? PBf[2*t]   : 0.0;
    double d = (t < 20) ? PBf[2*t+1] : 0.0;
    #pragma unroll
    for (int off = 32; off > 0; off >>= 1) {
      c += __shfl_down(c, off);
      d += __shfl_down(d, off);
    }
    if (t == 0) { ST[2] = c; ST[3] = d; }
  }
}

// ---------------------------------------------------------------------------
// Shared device helpers (round-1 proven versions): I-row compute (per-lane
// 8 ks, 4-lane groups, xor 1/2 = DPP only) and softmax-partials output.
// ---------------------------------------------------------------------------
__device__ __forceinline__ void irow_compute(const float* ypj, const float xp[8],
                                             const int kq, float4 p[10]) {
  #pragma unroll
  for (int m = 0; m < 10; ++m) {
    float4 acc;
    #pragma unroll
    for (int jj = 0; jj < 4; ++jj) {
      const int j = 4*m + jj;
      const float4 y0 = *(const float4*)(ypj + j*32 + kq*8);
      const float4 y1 = *(const float4*)(ypj + j*32 + kq*8 + 4);
      const float s = xp[0]*y0.x + xp[1]*y0.y + xp[2]*y0.z + xp[3]*y0.w
                    + xp[4]*y1.x + xp[5]*y1.y + xp[6]*y1.z + xp[7]*y1.w;
      if (jj==0) acc.x = s; else if (jj==1) acc.y = s; else if (jj==2) acc.z = s; else acc.w = s;
    }
    acc.x += __shfl_xor(acc.x,1); acc.x += __shfl_xor(acc.x,2);
    acc.y += __shfl_xor(acc.y,1); acc.y += __shfl_xor(acc.y,2);
    acc.z += __shfl_xor(acc.z,1); acc.z += __shfl_xor(acc.z,2);
    acc.w += __shfl_xor(acc.w,1); acc.w += __shfl_xor(acc.w,2);
    p[m] = acc;
  }
}

__device__ __forceinline__ void partials_out(const float4 p[10], const int t, const int kq,
    float* sredm, float* sreds, float* redm,
    float* __restrict__ PmB, float* __restrict__ PsB) {
  float ev[10];
  #pragma unroll
  for (int m = 0; m < 10; ++m) {
    const float4 qv = p[m];
    ev[m] = (kq&1) ? ((kq&2)? qv.w : qv.y) : ((kq&2)? qv.z : qv.x);
  }
  const int w = t >> 6, tl = t & 63;
  float mv[10];
  #pragma unroll
  for (int m = 0; m < 10; ++m) {
    mv[m] = ev[m];
    mv[m] = fmaxf(mv[m], __shfl_xor(mv[m], 4));
    mv[m] = fmaxf(mv[m], __shfl_xor(mv[m], 8));
    mv[m] = fmaxf(mv[m], __shfl_xor(mv[m], 16));
    mv[m] = fmaxf(mv[m], __shfl_xor(mv[m], 32));
  }
  if (tl < 4) {
    #pragma unroll
    for (int m = 0; m < 10; ++m) sredm[w*40 + 4*m + kq] = mv[m];
  }
  __syncthreads();
  if (t < 40)
    redm[t] = fmaxf(fmaxf(sredm[t], sredm[40+t]), fmaxf(sredm[80+t], sredm[120+t]));
  __syncthreads();
  float es[10];
  #pragma unroll
  for (int m = 0; m < 10; ++m) {
    const float M = redm[4*m + kq];
    es[m] = __expf(ev[m]-M);
    es[m] += __shfl_xor(es[m], 4);
    es[m] += __shfl_xor(es[m], 8);
    es[m] += __shfl_xor(es[m], 16);
    es[m] += __shfl_xor(es[m], 32);
  }
  if (tl < 4) {
    #pragma unroll
    for (int m = 0; m < 10; ++m) sreds[w*40 + 4*m + kq] = es[m];
  }
  __syncthreads();
  if (t < 40) {
    PmB[(size_t)t*64] = redm[t];
    PsB[(size_t)t*64] = sreds[t]+sreds[40+t]+sreds[80+t]+sreds[120+t];
  }
}

// ---------------------------------------------------------------------------
// K2: y_p directly from fe: yp = relu(q*relu(ry*(fe@Wv + cbV) - ry*my*csV)).
// ---------------------------------------------------------------------------
__global__ __launch_bounds__(256,4)
void k_yp2(const float* __restrict__ fe, const float* __restrict__ CW,
           const float* __restrict__ q, const double* __restrict__ ST,
           float* __restrict__ yp) {
  __shared__ float in_t[64*64];
  __shared__ float Wl[64*32];
  const int t = threadIdx.x;
  const int r0 = blockIdx.x * 64;
  #pragma unroll
  for (int s = 0; s < 4; ++s) {
    int f = (t + 256*s) * 4;
    int r = f >> 6, d = f & 63;
    float4 v = *(const float4*)(fe + (size_t)r0*FIN + f);
    *(float4*)(in_t + r*64 + (d ^ ((r & 7) * 8))) = v;
  }
  #pragma unroll
  for (int s = 0; s < 2; ++s) {
    int f = (t + 256*s) * 4;
    *(float4*)(Wl + f) = *(const float4*)(CW + CW_WV + f);
  }
  __syncthreads();
  const double cy = (double)YROWS * (double)C;
  const double myd = ST[2]/cy, vy = ST[3]/cy - myd*myd;
  const float ry = (float)(1.0/sqrt(vy + (double)EPS));
  const float mr = (float)myd * ry;
  const int r2 = t >> 2, kq = t & 3;
  const int swz = (r2 & 7) * 8;
  float acc[8] = {0,0,0,0,0,0,0,0};
  #pragma unroll
  for (int dc = 0; dc < 16; ++dc) {
    const int d = dc*4;
    const float4 a = *(const float4*)(in_t + r2*64 + (d ^ swz));
    { const float4 w0 = *(const float4*)(Wl + (d+0)*32 + kq*8);
      const float4 w1 = *(const float4*)(Wl + (d+0)*32 + kq*8 + 4); ACC8(acc, a.x, w0, w1); }
    { const float4 w0 = *(const float4*)(Wl + (d+1)*32 + kq*8);
      const float4 w1 = *(const float4*)(Wl + (d+1)*32 + kq*8 + 4); ACC8(acc, a.y, w0, w1); }
    { const float4 w0 = *(const float4*)(Wl + (d+2)*32 + kq*8);
      const float4 w1 = *(const float4*)(Wl + (d+2)*32 + kq*8 + 4); ACC8(acc, a.z, w0, w1); }
    { const float4 w0 = *(const float4*)(Wl + (d+3)*32 + kq*8);
      const float4 w1 = *(const float4*)(Wl + (d+3)*32 + kq*8 + 4); ACC8(acc, a.w, w0, w1); }
  }
  #pragma unroll
  for (int i = 0; i < 8; ++i) {
    const int k = kq*8 + i;
    const float typ = ry*(acc[i] + CW[CW_CBV+k]) - mr*CW[CW_CSV+k];
    float v = fmaxf(typ, 0.f);
    acc[i] = fmaxf(q[k]*v, 0.f);
  }
  *(float4*)(yp + (size_t)(r0+r2)*KK + kq*8)     = make_float4(acc[0],acc[1],acc[2],acc[3]);
  *(float4*)(yp + (size_t)(r0+r2)*KK + kq*8 + 4) = make_float4(acc[4],acc[5],acc[6],acc[7]);
}

// ---------------------------------------------------------------------------
// K3: layer-0 (round-1 proven): xu = rx*(nf@Wu + cbU) - rx*mx*csU, gx scalar,
// x_p = relu(xu), I row, softmax partials (64-wide).
// ---------------------------------------------------------------------------
__global__ __launch_bounds__(256,4)
void k_I0(const float* __restrict__ nf, const float* __restrict__ CW,
          const double* __restrict__ ST, const float* __restrict__ yp,
          float* __restrict__ XU, float* __restrict__ GX,
          float* __restrict__ Pm, float* __restrict__ Ps) {
  __shared__ float in_t[64*64];
  __shared__ float Wl[64*32];
  __shared__ float ypj[40*32];
  __shared__ float wgl[64];
  __shared__ float sredm[160], sreds[160], redm[40];
  const int t = threadIdx.x;
  const int bid = blockIdx.x;
  const int b = bid >> 6, blk = bid & 63;
  const size_t rowbase = (size_t)b*NPG + (size_t)blk*64;
  #pragma unroll
  for (int s = 0; s < 4; ++s) {
    int f = (t + 256*s) * 4;
    int r = f >> 6, d = f & 63;
    float4 v = *(const float4*)(nf + rowbase*FIN + f);
    *(float4*)(in_t + r*64 + (d ^ ((r & 7) * 8))) = v;
  }
  #pragma unroll
  for (int s = 0; s < 2; ++s) {
    int f = (t + 256*s) * 4;
    *(float4*)(Wl + f) = *(const float4*)(CW + CW_WU + f);
  }
  for (int f4v = t; f4v < 320; f4v += 256)
    *(float4*)(ypj + f4v*4) = *(const float4*)(yp + (size_t)b*(JJ*KK) + f4v*4);
  if (t < 64) wgl[t] = CW[CW_WG + t];
  __syncthreads();
  const double cx = (double)NTOT * (double)C;
  const double mx = ST[0]/cx, vx = ST[1]/cx - mx*mx;
  const float rx = (float)(1.0/sqrt(vx + (double)EPS));
  const float mr = (float)mx * rx;
  const int r2 = t >> 2, kq = t & 3;
  const int swz = (r2 & 7) * 8;
  float acc[8] = {0,0,0,0,0,0,0,0};
  #pragma unroll
  for (int dc = 0; dc < 16; ++dc) {
    const int d = dc*4;
    const float4 a = *(const float4*)(in_t + r2*64 + (d ^ swz));
    { const float4 w0 = *(const float4*)(Wl + (d+0)*32 + kq*8);
      const float4 w1 = *(const float4*)(Wl + (d+0)*32 + kq*8 + 4); ACC8(acc, a.x, w0, w1); }
    { const float4 w0 = *(const float4*)(Wl + (d+1)*32 + kq*8);
      const float4 w1 = *(const float4*)(Wl + (d+1)*32 + kq*8 + 4); ACC8(acc, a.y, w0, w1); }
    { const float4 w0 = *(const float4*)(Wl + (d+2)*32 + kq*8);
      const float4 w1 = *(const float4*)(Wl + (d+2)*32 + kq*8 + 4); ACC8(acc, a.z, w0, w1); }
    { const float4 w0 = *(const float4*)(Wl + (d+3)*32 + kq*8);
      const float4 w1 = *(const float4*)(Wl + (d+3)*32 + kq*8 + 4); ACC8(acc, a.w, w0, w1); }
  }
  // gx partial over this lane's d-range, reduce over group
  float gp = 0.f;
  #pragma unroll
  for (int u = 0; u < 4; ++u) {
    const int d = kq*16 + 4*u;
    const float4 a = *(const float4*)(in_t + r2*64 + (d ^ swz));
    const float4 w = *(const float4*)(wgl + d);
    gp += a.x*w.x + a.y*w.y + a.z*w.z + a.w*w.w;
  }
  gp += __shfl_xor(gp, 1); gp += __shfl_xor(gp, 2);
  float xp[8];
  #pragma unroll
  for (int i = 0; i < 8; ++i) {
    const int k = kq*8 + i;
    const float xv = rx*(acc[i] + CW[CW_CBU+k]) - mr*CW[CW_CSU+k];
    acc[i] = xv;
    xp[i] = fmaxf(xv, 0.f);
  }
  *(float4*)(XU + (rowbase+r2)*KK + kq*8)     = make_float4(acc[0],acc[1],acc[2],acc[3]);
  *(float4*)(XU + (rowbase+r2)*KK + kq*8 + 4) = make_float4(acc[4],acc[5],acc[6],acc[7]);
  if (kq == 0) GX[rowbase + r2] = rx*(gp + CW[CW_SC+0]) - mr*CW[CW_SC+1];
  float4 p[10];
  irow_compute(ypj, xp, kq, p);
  partials_out(p, t, kq, sredm, sreds, redm,
               Pm + (size_t)b*2560 + blk, Ps + (size_t)b*2560 + blk);
}

// ---------------------------------------------------------------------------
// K4: fused layer update in K-space (round-1 proven structure):
// comb (LDS-staged transpose) -> I from xu -> A -> h = A@yp -> hu = h@VU,
// gate -> blend -> new I -> partials (or FINAL: out = sigmoid(sum_j I^2)).
// ---------------------------------------------------------------------------
template<int FINAL>
__global__ __launch_bounds__(256,4)
void k_fused2(float* __restrict__ XU, float* __restrict__ GX,
              const float* __restrict__ yp, const float* __restrict__ CW,
              const float* __restrict__ gb,
              const float* __restrict__ PmIn, const float* __restrict__ PsIn,
              float* __restrict__ PmOut, float* __restrict__ PsOut,
              float* __restrict__ outp) {
  __shared__ float ypj[40*32];
  __shared__ float e_l[64*44];           // comb pmT stage -> A-tile -> partials overlay
  __shared__ float h_l[64*40];           // comb psT stage -> h-tile
  __shared__ float VUl[32*32];
  __shared__ float M_l[40], Si_l[40];
  __shared__ float vgxl[32], vghl[32];
  float* sredm = e_l;
  float* sreds = e_l + 160;
  float* redm  = e_l + 320;
  const int t = threadIdx.x;
  const int bid = blockIdx.x;
  const int b = bid >> 6, blk = bid & 63;
  const size_t rowbase = (size_t)b*NPG + (size_t)blk*64;
  // stage partials transposed: pmT[blk][j] in e_l, psT[blk][j] in h_l
  for (int f4v = t; f4v < 640; f4v += 256) {
    const int j = f4v >> 4;              // (4*f4v)/64
    const int c0 = (4*f4v) & 63;
    const float4 pm4 = *(const float4*)(PmIn + (size_t)b*2560 + 4*f4v);
    const float4 ps4 = *(const float4*)(PsIn + (size_t)b*2560 + 4*f4v);
    e_l[(c0+0)*40 + j] = pm4.x; e_l[(c0+1)*40 + j] = pm4.y;
    e_l[(c0+2)*40 + j] = pm4.z; e_l[(c0+3)*40 + j] = pm4.w;
    h_l[(c0+0)*40 + j] = ps4.x; h_l[(c0+1)*40 + j] = ps4.y;
    h_l[(c0+2)*40 + j] = ps4.z; h_l[(c0+3)*40 + j] = ps4.w;
  }
  for (int f4v = t; f4v < 320; f4v += 256)
    *(float4*)(ypj + f4v*4) = *(const float4*)(yp + (size_t)b*(JJ*KK) + f4v*4);
  *(float4*)(VUl + 4*t) = *(const float4*)(CW + CW_VU + 4*t);
  if (t < 32) { vgxl[t] = CW[CW_VGX+t]; vghl[t] = CW[CW_VGH+t]; }
  __syncthreads();
  if (t < 40) {
    float M = 0.f;
    for (int k2 = 0; k2 < 64; ++k2) M = fmaxf(M, e_l[k2*40 + t]);
    float S = 0.f;
    for (int k2 = 0; k2 < 64; ++k2) S += h_l[k2*40 + t]*__expf(e_l[k2*40 + t]-M);
    M_l[t] = M; Si_l[t] = 1.f/S;
  }
  const int r2 = t >> 2, kq = t & 3;
  float xu[8];
  {
    const float4 x0 = *(const float4*)(XU + (rowbase+r2)*KK + kq*8);
    const float4 x1 = *(const float4*)(XU + (rowbase+r2)*KK + kq*8 + 4);
    xu[0]=x0.x; xu[1]=x0.y; xu[2]=x0.z; xu[3]=x0.w;
    xu[4]=x1.x; xu[5]=x1.y; xu[6]=x1.z; xu[7]=x1.w;
  }
  const float gx = GX[rowbase + r2];
  float xp[8];
  #pragma unroll
  for (int i = 0; i < 8; ++i) xp[i] = fmaxf(xu[i], 0.f);
  __syncthreads();                       // M_l/Si_l ready; e_l/h_l stages dead
  float4 p[10];
  irow_compute(ypj, xp, kq, p);          // bitwise == I used for PmIn/PsIn
  // A = exp(I-M)*Si ; lane writes only its designated float4s of the e-tile
  #pragma unroll
  for (int m = 0; m < 10; ++m) {
    if ((m & 3) == kq) {
      float4 e4;
      e4.x = __expf(p[m].x - M_l[4*m+0]) * Si_l[4*m+0];
      e4.y = __expf(p[m].y - M_l[4*m+1]) * Si_l[4*m+1];
      e4.z = __expf(p[m].z - M_l[4*m+2]) * Si_l[4*m+2];
      e4.w = __expf(p[m].w - M_l[4*m+3]) * Si_l[4*m+3];
      *(float4*)(e_l + r2*44 + 4*m) = e4;
    }
  }
  __syncthreads();
  // phase B: h[n][k] = sum_j A[n][j]*yp[j][k]  (rows {rq, rq+32}, k = kc*4..+3)
  {
    const int rq = t >> 3, kc = t & 7;
    float4 h0 = make_float4(0.f,0.f,0.f,0.f), h1 = make_float4(0.f,0.f,0.f,0.f);
    #pragma unroll 4
    for (int j = 0; j < JJ; ++j) {
      const float4 yv = *(const float4*)(ypj + j*32 + kc*4);
      const float e0 = e_l[rq*44 + j];
      const float e1 = e_l[(rq+32)*44 + j];
      h0.x += e0*yv.x; h0.y += e0*yv.y; h0.z += e0*yv.z; h0.w += e0*yv.w;
      h1.x += e1*yv.x; h1.y += e1*yv.y; h1.z += e1*yv.z; h1.w += e1*yv.w;
    }
    h0.x = fmaxf(h0.x,0.f); h0.y = fmaxf(h0.y,0.f); h0.z = fmaxf(h0.z,0.f); h0.w = fmaxf(h0.w,0.f);
    h1.x = fmaxf(h1.x,0.f); h1.y = fmaxf(h1.y,0.f); h1.z = fmaxf(h1.z,0.f); h1.w = fmaxf(h1.w,0.f);
    *(float4*)(h_l + rq*40 + kc*4) = h0;
    *(float4*)(h_l + (rq+32)*40 + kc*4) = h1;
  }
  __syncthreads();
  // phase C: hu = h@VU, gate, blend in K-space
  float hu[8] = {0,0,0,0,0,0,0,0};
  float gh2 = 0.f, ghx = 0.f;
  #pragma unroll 8
  for (int kp = 0; kp < KK; ++kp) {
    const float hv = h_l[r2*40 + kp];
    gh2 += hv * vghl[kp];
    ghx += hv * vgxl[kp];
    const float4 v0 = *(const float4*)(VUl + kp*32 + kq*8);
    const float4 v1 = *(const float4*)(VUl + kp*32 + kq*8 + 4);
    ACC8(hu, hv, v0, v1);
  }
  const float z = 1.f/(1.f + __expf(-(gx + gh2 + gb[0])));
  #pragma unroll
  for (int i = 0; i < 8; ++i) {
    xu[i] = (1.f - z)*xu[i] + z*hu[i];
    xp[i] = fmaxf(xu[i], 0.f);
  }
  if (!FINAL) {
    *(float4*)(XU + (rowbase+r2)*KK + kq*8)     = make_float4(xu[0],xu[1],xu[2],xu[3]);
    *(float4*)(XU + (rowbase+r2)*KK + kq*8 + 4) = make_float4(xu[4],xu[5],xu[6],xu[7]);
    if (kq == 0) GX[rowbase + r2] = (1.f - z)*gx + z*ghx;
  }
  // next-layer I
  irow_compute(ypj, xp, kq, p);
  if (FINAL) {
    float s = 0.f;
    #pragma unroll
    for (int m = 0; m < 10; ++m)
      s += p[m].x*p[m].x + p[m].y*p[m].y + p[m].z*p[m].z + p[m].w*p[m].w;
    if (kq == 0) outp[rowbase + r2] = 1.f/(1.f + __expf(-s));
    return;
  }
  partials_out(p, t, kq, sredm, sreds, redm,
               PmOut + (size_t)b*2560 + blk, PsOut + (size_t)b*2560 + blk);
}

extern "C" void kernel_launch(void* const* d_in, const int* in_sizes, int n_in,
                              void* d_out, int out_size, void* d_ws, size_t ws_size,
                              hipStream_t stream) {
  const float* nf  = (const float*)d_in[0];
  const float* fe  = (const float*)d_in[1];
  const float* W   = (const float*)d_in[2];
  const float* bin = (const float*)d_in[3];
  const float* U   = (const float*)d_in[4];
  const float* V   = (const float*)d_in[5];
  const float* q   = (const float*)d_in[6];
  const float* gw  = (const float*)d_in[7];
  const float* gb  = (const float*)d_in[8];
  float* out = (float*)d_out;
  float* wf  = (float*)d_ws;

  float* XU  = wf + XU_OFF;
  float* GX  = wf + GX_OFF;
  float* YP  = wf + YP_OFF;
  float* PMa = wf + PMA_OFF;
  float* PSa = wf + PSA_OFF;
  float* PMb = wf + PMB_OFF;
  float* PSb = wf + PSB_OFF;
  float* CWp = wf + CWS_OFF;
  double* PBn = (double*)(wf + PBN_OFF);
  double* PBf = (double*)(wf + PBF_OFF);
  double* ST  = (double*)(wf + ST_OFF);

  k_pre<<<2, 256, 0, stream>>>(W, bin, U, V, gw, CWp);
  k_cov<<<512, 256, 0, stream>>>(nf, CWp, PBn, NTOT/64);
  k_cov<<<20, 256, 0, stream>>>(fe, CWp, PBf, YROWS/64);
  k_comb<<<1, 256, 0, stream>>>(PBn, PBf, ST);
  k_yp2<<<YROWS/64, 256, 0, stream>>>(fe, CWp, q, ST, YP);
  k_I0<<<NTOT/64, 256, 0, stream>>>(nf, CWp, ST, YP, XU, GX, PMa, PSa);
  k_fused2<0><<<NTOT/64, 256, 0, stream>>>(XU, GX, YP, CWp, gb, PMa, PSa, PMb, PSb, nullptr);
  k_fused2<1><<<NTOT/64, 256, 0, stream>>>(XU, GX, YP, CWp, gb, PMb, PSb, nullptr, nullptr, out);
}